// Round 1
// baseline (699.839 us; speedup 1.0000x reference)
//
#include <hip/hip_runtime.h>
#include <hip/hip_bf16.h>

// ---- problem constants (match reference) ----
#define TS 8192     // tokens S
#define TM 4096     // model dim M
#define TE 64       // experts E
#define TCAP 128    // capacity
static const size_t CW = (size_t)TS * TE * TCAP;   // 67108864 elems per big output
// exact output footprint: l_aux + combine + dispatch + exp_counts
static const size_t OUT_ELEMS = 1 + 2 * CW + TE;   // 134,217,793 floats
static const size_t OUT_BYTES = OUT_ELEMS * sizeof(float);  // 536,871,172 B

// ================= GEMM: logits partials, split-K =================
// C[8192,64] = x[8192,4096] . wg[64,4096]^T, fp32, deterministic.
// grid: (32 token-blocks of 256, KS k-chunks). 256 threads, 8x8 reg tile.
#define BM 256
#define BK 16
#define SA 260   // As row stride (floats): 1040B, 16B aligned, conflict-free pattern
#define SW 68    // Ws row stride: 272B

__global__ __launch_bounds__(256) void gemm_partial(
    const float* __restrict__ x, const float* __restrict__ wg,
    float* __restrict__ part, int kchunk) {
  __shared__ float As[BK][SA];   // [k][token]
  __shared__ float Ws[BK][SW];   // [k][expert]
  const int tid = threadIdx.x;
  const int t0 = blockIdx.x * BM;
  const int k0 = blockIdx.y * kchunk;
  const int ntile = kchunk / BK;
  const int tg = tid >> 3;       // token group 0..31 -> 8 tokens
  const int eg = tid & 7;        // expert group 0..7 -> 8 experts

  float acc[8][8] = {};
  float4 ra[4]; float4 rw;

  // A tile: 256 tok x 16 k = 4096 floats = 1024 f4, 4/thread
  // mapping: idx = tid + 256*i -> tok=idx>>2, c4=idx&3 (coalesced along k)
  // W tile: 64 e x 16 k = 256 f4, 1/thread: e=tid>>2, c4=tid&3
  auto load_tile = [&](int kt) {
    const int kb = k0 + kt * BK;
#pragma unroll
    for (int i = 0; i < 4; i++) {
      int idx = tid + 256 * i;
      int tok = idx >> 2, c4 = idx & 3;
      ra[i] = *(const float4*)&x[(size_t)(t0 + tok) * TM + kb + 4 * c4];
    }
    int e = tid >> 2, c4 = tid & 3;
    rw = *(const float4*)&wg[(size_t)e * TM + kb + 4 * c4];
  };

  load_tile(0);
  for (int kt = 0; kt < ntile; kt++) {
    // regs -> LDS (transposed to [k][m]/[k][e]; 2-way bank alias only = free)
#pragma unroll
    for (int i = 0; i < 4; i++) {
      int idx = tid + 256 * i;
      int tok = idx >> 2, c4 = idx & 3;
      As[4 * c4 + 0][tok] = ra[i].x; As[4 * c4 + 1][tok] = ra[i].y;
      As[4 * c4 + 2][tok] = ra[i].z; As[4 * c4 + 3][tok] = ra[i].w;
    }
    { int e = tid >> 2, c4 = tid & 3;
      Ws[4 * c4 + 0][e] = rw.x; Ws[4 * c4 + 1][e] = rw.y;
      Ws[4 * c4 + 2][e] = rw.z; Ws[4 * c4 + 3][e] = rw.w; }
    __syncthreads();
    if (kt + 1 < ntile) load_tile(kt + 1);  // prefetch overlaps compute
#pragma unroll
    for (int k = 0; k < BK; k++) {
      float4 a0 = *(const float4*)&As[k][tg * 8];
      float4 a1 = *(const float4*)&As[k][tg * 8 + 4];
      float4 b0 = *(const float4*)&Ws[k][eg * 8];
      float4 b1 = *(const float4*)&Ws[k][eg * 8 + 4];
      float av[8] = {a0.x, a0.y, a0.z, a0.w, a1.x, a1.y, a1.z, a1.w};
      float bv[8] = {b0.x, b0.y, b0.z, b0.w, b1.x, b1.y, b1.z, b1.w};
#pragma unroll
      for (int i = 0; i < 8; i++)
#pragma unroll
        for (int j = 0; j < 8; j++) acc[i][j] += av[i] * bv[j];
    }
    __syncthreads();
  }
  // write this k-chunk's partial: part[ky][token][expert]
  float* dst = part + (size_t)blockIdx.y * TS * TE;
#pragma unroll
  for (int i = 0; i < 8; i++) {
    int tok = t0 + tg * 8 + i;
#pragma unroll
    for (int j = 0; j < 8; j += 4) {
      float4 v = make_float4(acc[i][j], acc[i][j + 1], acc[i][j + 2], acc[i][j + 3]);
      *(float4*)&dst[(size_t)tok * TE + eg * 8 + j] = v;
    }
  }
}

// ============ softmax + argmax (one wave per token) ============
__global__ __launch_bounds__(256) void softmax_top1(
    const float* __restrict__ part, int KS,
    float* __restrict__ gates, float* __restrict__ gate1, int* __restrict__ idx1) {
  const int s = blockIdx.x * 4 + (threadIdx.x >> 6);
  const int lane = threadIdx.x & 63;
  float logit = 0.0f;
  for (int p = 0; p < KS; p++)
    logit += part[((size_t)p * TS + s) * TE + lane];   // deterministic order

  // wave argmax, first-index tie-break (matches jnp.argmax)
  float mv = logit; int mi = lane;
#pragma unroll
  for (int off = 32; off; off >>= 1) {
    float ov = __shfl_xor(mv, off);
    int oi = __shfl_xor(mi, off);
    if (ov > mv || (ov == mv && oi < mi)) { mv = ov; mi = oi; }
  }
  float ex = expf(logit - mv);
  float sum = ex;
#pragma unroll
  for (int off = 32; off; off >>= 1) sum += __shfl_xor(sum, off);
  float g = ex / sum;
  gates[(size_t)s * TE + lane] = g;
  if (lane == mi) { gate1[s] = g; idx1[s] = mi; }
}

// ============ me[e] = sum_s gates[s][e], deterministic tree ============
__global__ __launch_bounds__(256) void me_reduce(const float* __restrict__ gates,
                                                 float* __restrict__ me) {
  const int e = blockIdx.x, tid = threadIdx.x;
  float s = 0.0f;
  for (int t = tid; t < TS; t += 256) s += gates[(size_t)t * TE + e];
  __shared__ float red[256];
  red[tid] = s; __syncthreads();
  for (int o = 128; o; o >>= 1) { if (tid < o) red[tid] += red[tid + o]; __syncthreads(); }
  if (tid == 0) me[e] = red[0];
}

// ==== capacity drop: rank tokens per expert in token order (1 wave/expert) ====
__global__ void capacity_rank(const int* __restrict__ idx1,
                              int* __restrict__ pos, int* __restrict__ counts) {
  const int e = blockIdx.x, lane = threadIdx.x;  // 64 threads
  int base = 0;
  for (int c = 0; c < TS / 64; c++) {
    int s = c * 64 + lane;
    bool m = (idx1[s] == e);
    unsigned long long mask = __ballot(m);
    if (m) {
      int p = base + __popcll(mask & ((1ull << lane) - 1ull));
      pos[s] = (p < TCAP) ? p : -1;   // each token owned by exactly one expert
    }
    base += __popcll(mask);
  }
  if (lane == 0) counts[e] = base;    // pre-drop exp_counts
}

// ============ l_aux scalar + exp_counts tail ============
__global__ void finalize_laux(const float* __restrict__ me, const int* __restrict__ counts,
                              float* __restrict__ out, size_t cw) {
  const int lane = threadIdx.x;  // 64
  float v = (me[lane] / (float)TS) * ((float)counts[lane] / (float)TS);
  float sum = v;
#pragma unroll
  for (int off = 32; off; off >>= 1) sum += __shfl_xor(sum, off);
  if (lane == 0) out[0] = sum * (float)TE;
  out[1 + 2 * cw + lane] = (float)counts[lane];
}

// ============ scatter nonzeros into combine/dispatch ============
__global__ __launch_bounds__(256) void scatter_out(
    const float* __restrict__ gate1, const int* __restrict__ idx1,
    const int* __restrict__ pos, float* __restrict__ out, size_t cw) {
  const int s = blockIdx.x * 256 + threadIdx.x;
  int p = pos[s];
  if (p >= 0) {
    size_t off = 1 + ((size_t)s * TE + idx1[s]) * (size_t)TCAP + (size_t)p;
    out[off] = gate1[s];        // combine_weights
    out[off + cw] = 1.0f;       // dispatch_mask
  }
}

extern "C" void kernel_launch(void* const* d_in, const int* in_sizes, int n_in,
                              void* d_out, int out_size, void* d_ws, size_t ws_size,
                              hipStream_t stream) {
  const float* x = (const float*)d_in[0];
  const float* wg = (const float*)d_in[1];
  float* out = (float*)d_out;

  const size_t SE = (size_t)TS * TE;
  // pick split-K to fit workspace (deterministic partials)
  int KS = 8;
  auto need = [&](int ks) {
    return (size_t)ks * SE * 4 + SE * 4 + (size_t)TS * 12 + 1024;
  };
  while (KS > 1 && need(KS) > ws_size) KS >>= 1;

  float* part  = (float*)d_ws;            // [KS][S][E]
  float* gates = part + (size_t)KS * SE;  // [S][E]
  float* gate1 = gates + SE;              // [S]
  int*   idx1  = (int*)(gate1 + TS);      // [S]
  int*   pos   = idx1 + TS;               // [S]
  float* me    = (float*)(pos + TS);      // [E]
  int*   cnts  = (int*)(me + TE);         // [E]

  // Zero EXACTLY the output footprint (compile-time constant: 536,871,172 B).
  // Previous code used out_size*sizeof(float); if out_size is in BYTES that
  // memsets 4x too much (2.147 GB == the observed 345us fill dispatch).
  hipMemsetAsync(d_out, 0, OUT_BYTES, stream);

  dim3 ggrid(TS / BM, KS);
  gemm_partial<<<ggrid, 256, 0, stream>>>(x, wg, part, TM / KS);
  softmax_top1<<<TS / 4, 256, 0, stream>>>(part, KS, gates, gate1, idx1);
  me_reduce<<<TE, 256, 0, stream>>>(gates, me);
  capacity_rank<<<TE, 64, 0, stream>>>(idx1, pos, cnts);
  finalize_laux<<<1, 64, 0, stream>>>(me, cnts, out, CW);
  scatter_out<<<TS / 256, 256, 0, stream>>>(gate1, idx1, pos, out, CW);
}

// Round 2
// 684.160 us; speedup vs baseline: 1.0229x; 1.0229x over previous
//
#include <hip/hip_runtime.h>
#include <hip/hip_bf16.h>

// ---- problem constants (match reference) ----
#define TS 8192     // tokens S
#define TM 4096     // model dim M
#define TE 64       // experts E
#define TCAP 128    // capacity
static const size_t CW = (size_t)TS * TE * TCAP;   // 67108864 elems per big output
static const size_t OUT_ELEMS = 1 + 2 * CW + TE;   // 134,217,793 floats
static const size_t OUT_BYTES = OUT_ELEMS * sizeof(float);  // 536,871,172 B

// ================= GEMM: logits partials, split-K =================
// C[8192,64] = x[8192,4096] . wg[64,4096]^T, fp32, deterministic.
// BM=128 -> grid (64 token-blocks, KS chunks) = 512 blocks = 2 blocks/CU
// (8 waves/CU, vs 4 before). Per-output fmac chain order is UNCHANGED
// (ascending k within chunk, chunks ascending) -> logits bitwise identical.
#define BM 128
#define BK 16
#define SA 132   // As row stride (floats): 2-way bank alias on write = free
#define SW 68    // Ws row stride

__global__ __launch_bounds__(256) void gemm_partial(
    const float* __restrict__ x, const float* __restrict__ wg,
    float* __restrict__ part, int kchunk) {
  __shared__ float As[BK][SA];   // [k][token]
  __shared__ float Ws[BK][SW];   // [k][expert]
  const int tid = threadIdx.x;
  const int t0 = blockIdx.x * BM;
  const int k0 = blockIdx.y * kchunk;
  const int ntile = kchunk / BK;
  const int tg = tid >> 3;       // token group 0..31 -> 4 tokens
  const int eg = tid & 7;        // expert group 0..7 -> 8 experts

  float acc[4][8] = {};
  float4 ra[2]; float4 rw;

  // A tile: 128 tok x 16 k = 512 f4, 2/thread: idx = tid + 256*i,
  //   tok = idx>>2, c4 = idx&3 (coalesced along k)
  // W tile: 64 e x 16 k = 256 f4, 1/thread: e = tid>>2, c4 = tid&3
  auto load_tile = [&](int kt) {
    const int kb = k0 + kt * BK;
#pragma unroll
    for (int i = 0; i < 2; i++) {
      int idx = tid + 256 * i;
      int tok = idx >> 2, c4 = idx & 3;
      ra[i] = *(const float4*)&x[(size_t)(t0 + tok) * TM + kb + 4 * c4];
    }
    int e = tid >> 2, c4 = tid & 3;
    rw = *(const float4*)&wg[(size_t)e * TM + kb + 4 * c4];
  };

  load_tile(0);
  for (int kt = 0; kt < ntile; kt++) {
    // regs -> LDS (transposed to [k][m]/[k][e]; 2-way bank alias = free)
#pragma unroll
    for (int i = 0; i < 2; i++) {
      int idx = tid + 256 * i;
      int tok = idx >> 2, c4 = idx & 3;
      As[4 * c4 + 0][tok] = ra[i].x; As[4 * c4 + 1][tok] = ra[i].y;
      As[4 * c4 + 2][tok] = ra[i].z; As[4 * c4 + 3][tok] = ra[i].w;
    }
    { int e = tid >> 2, c4 = tid & 3;
      Ws[4 * c4 + 0][e] = rw.x; Ws[4 * c4 + 1][e] = rw.y;
      Ws[4 * c4 + 2][e] = rw.z; Ws[4 * c4 + 3][e] = rw.w; }
    __syncthreads();
    if (kt + 1 < ntile) load_tile(kt + 1);  // prefetch overlaps compute
#pragma unroll
    for (int k = 0; k < BK; k++) {
      float4 a0 = *(const float4*)&As[k][tg * 4];
      float4 b0 = *(const float4*)&Ws[k][eg * 8];
      float4 b1 = *(const float4*)&Ws[k][eg * 8 + 4];
      float av[4] = {a0.x, a0.y, a0.z, a0.w};
      float bv[8] = {b0.x, b0.y, b0.z, b0.w, b1.x, b1.y, b1.z, b1.w};
#pragma unroll
      for (int i = 0; i < 4; i++)
#pragma unroll
        for (int j = 0; j < 8; j++) acc[i][j] += av[i] * bv[j];
    }
    __syncthreads();
  }
  // write this k-chunk's partial: part[ky][token][expert]
  float* dst = part + (size_t)blockIdx.y * TS * TE;
#pragma unroll
  for (int i = 0; i < 4; i++) {
    int tok = t0 + tg * 4 + i;
#pragma unroll
    for (int j = 0; j < 8; j += 4) {
      float4 v = make_float4(acc[i][j], acc[i][j + 1], acc[i][j + 2], acc[i][j + 3]);
      *(float4*)&dst[(size_t)tok * TE + eg * 8 + j] = v;
    }
  }
}

// ============ softmax + argmax (one wave per token) ============
__global__ __launch_bounds__(256) void softmax_top1(
    const float* __restrict__ part, int KS,
    float* __restrict__ gates, float* __restrict__ gate1, int* __restrict__ idx1) {
  const int s = blockIdx.x * 4 + (threadIdx.x >> 6);
  const int lane = threadIdx.x & 63;
  float logit = 0.0f;
  for (int p = 0; p < KS; p++)
    logit += part[((size_t)p * TS + s) * TE + lane];   // deterministic order

  // wave argmax, first-index tie-break (matches jnp.argmax)
  float mv = logit; int mi = lane;
#pragma unroll
  for (int off = 32; off; off >>= 1) {
    float ov = __shfl_xor(mv, off);
    int oi = __shfl_xor(mi, off);
    if (ov > mv || (ov == mv && oi < mi)) { mv = ov; mi = oi; }
  }
  float ex = expf(logit - mv);
  float sum = ex;
#pragma unroll
  for (int off = 32; off; off >>= 1) sum += __shfl_xor(sum, off);
  float g = ex / sum;
  gates[(size_t)s * TE + lane] = g;
  if (lane == mi) { gate1[s] = g; idx1[s] = mi; }
}

// ==== fused stats: me[e] reduction + capacity rank (one block per expert) ====
// me: identical 256-thread strided sum + tree as before (bitwise-same result).
// rank: wave 0 only, identical ballot scan as before.
__global__ __launch_bounds__(256) void stats(
    const float* __restrict__ gates, const int* __restrict__ idx1,
    float* __restrict__ me, int* __restrict__ pos, int* __restrict__ counts) {
  const int e = blockIdx.x, tid = threadIdx.x;
  float s = 0.0f;
  for (int t = tid; t < TS; t += 256) s += gates[(size_t)t * TE + e];
  __shared__ float red[256];
  red[tid] = s; __syncthreads();
  for (int o = 128; o; o >>= 1) { if (tid < o) red[tid] += red[tid + o]; __syncthreads(); }
  if (tid == 0) me[e] = red[0];

  if (tid < 64) {                      // wave 0: rank tokens for expert e
    const int lane = tid;
    int base = 0;
    for (int c = 0; c < TS / 64; c++) {
      int sTok = c * 64 + lane;
      bool m = (idx1[sTok] == e);
      unsigned long long mask = __ballot(m);
      if (m) {
        int p = base + __popcll(mask & ((1ull << lane) - 1ull));
        pos[sTok] = (p < TCAP) ? p : -1;   // each token owned by exactly one expert
      }
      base += __popcll(mask);
    }
    if (lane == 0) counts[e] = base;    // pre-drop exp_counts
  }
}

// ===== scatter nonzeros + (extra block) l_aux scalar + exp_counts tail =====
__global__ __launch_bounds__(256) void scatter_out(
    const float* __restrict__ gate1, const int* __restrict__ idx1,
    const int* __restrict__ pos, const float* __restrict__ me,
    const int* __restrict__ counts, float* __restrict__ out, size_t cw) {
  if (blockIdx.x == TS / 256) {        // tail block: l_aux + exp_counts
    const int lane = threadIdx.x;
    if (lane < 64) {
      float v = (me[lane] / (float)TS) * ((float)counts[lane] / (float)TS);
      float sum = v;
#pragma unroll
      for (int off = 32; off; off >>= 1) sum += __shfl_xor(sum, off);
      if (lane == 0) out[0] = sum * (float)TE;
      out[1 + 2 * cw + lane] = (float)counts[lane];
    }
    return;
  }
  const int s = blockIdx.x * 256 + threadIdx.x;
  int p = pos[s];
  if (p >= 0) {
    size_t off = 1 + ((size_t)s * TE + idx1[s]) * (size_t)TCAP + (size_t)p;
    out[off] = gate1[s];        // combine_weights
    out[off + cw] = 1.0f;       // dispatch_mask
  }
}

extern "C" void kernel_launch(void* const* d_in, const int* in_sizes, int n_in,
                              void* d_out, int out_size, void* d_ws, size_t ws_size,
                              hipStream_t stream) {
  const float* x = (const float*)d_in[0];
  const float* wg = (const float*)d_in[1];
  float* out = (float*)d_out;

  const size_t SE = (size_t)TS * TE;
  // pick split-K to fit workspace (deterministic partials); KS=8 preserved
  // (changing KS changes fp32 summation grouping -> logits no longer bitwise
  //  identical to reference; absmax is currently exactly 0.0, keep it).
  int KS = 8;
  auto need = [&](int ks) {
    return (size_t)ks * SE * 4 + SE * 4 + (size_t)TS * 12 + 1024;
  };
  while (KS > 1 && need(KS) > ws_size) KS >>= 1;

  float* part  = (float*)d_ws;            // [KS][S][E]
  float* gates = part + (size_t)KS * SE;  // [S][E]
  float* gate1 = gates + SE;              // [S]
  int*   idx1  = (int*)(gate1 + TS);      // [S]
  int*   pos   = idx1 + TS;               // [S]
  float* me    = (float*)(pos + TS);      // [E]
  int*   cnts  = (int*)(me + TE);         // [E]

  // zero exactly the 537MB output; only <=8192 nonzeros exist, scattered after
  hipMemsetAsync(d_out, 0, OUT_BYTES, stream);

  dim3 ggrid(TS / BM, KS);
  gemm_partial<<<ggrid, 256, 0, stream>>>(x, wg, part, TM / KS);
  softmax_top1<<<TS / 4, 256, 0, stream>>>(part, KS, gates, gate1, idx1);
  stats<<<TE, 256, 0, stream>>>(gates, idx1, me, pos, cnts);
  scatter_out<<<TS / 256 + 1, 256, 0, stream>>>(gate1, idx1, pos, me, cnts, out, CW);
}